// Round 3
// baseline (196.740 us; speedup 1.0000x reference)
//
#include <hip/hip_runtime.h>

// ---------------------------------------------------------------------------
// DigitConvolutionalModel: x(32768,784) -> conv3x3(valid) -> 676
//   -> relu(@W1(676,300)+b1) -> relu(@W2(300,300)+b2) -> @W3(300,10)+b3
//
// R9: shrink the barrier domain + register diet.
//  - 256-thr blocks (4 waves), 32 rows/block, 1024 blocks. Wave w: 2 m-tiles
//    x 5 n-tiles (uniform, acc=40 AGPR). B frags per-wave from L2.
//  - LDS = 20.8KB UNION: Abuf dbuf (2x32x136 bf16, 17KB) overlays padded
//    hbuf ([20][65] bf16x8). 4-5 independent blocks/CU, each with its own
//    4-wave barrier -> stalls interleave across blocks.
//  - hbuf frag stride 65 (1040B): h-store bank conflict 8-way -> ~4-way;
//    GEMM2/3 reads stay lane-consecutive (conflict-free).
//  - raw s_barrier (lgkmcnt-only) everywhere; x pf stays in flight.
//  - prep_weights reverted to R6 per-element (363K threads): R7's 8x TLP
//    cut was a latency-bound regression (bench 190.1 -> 197.4).
// ---------------------------------------------------------------------------

typedef __bf16 bf16_t;
typedef __bf16 bf16x4 __attribute__((ext_vector_type(4)));
typedef __bf16 bf16x8 __attribute__((ext_vector_type(8)));
typedef float  f32x4  __attribute__((ext_vector_type(4)));

#define MFMA16(a, b, c) __builtin_amdgcn_mfma_f32_16x16x32_bf16((a), (b), (c), 0, 0, 0)

#define W1F_ELEMS (25 * 20 * 64 * 8)  // 256000  (K=800, N=320)
#define W2F_ELEMS (10 * 20 * 64 * 8)  // 102400  (K=320, N=320)
#define W3F_ELEMS (10 * 1 * 64 * 8)   // 5120    (K=320, N=16)
#define ASTRIDE   136                 // bf16 row stride in Abuf (272B)
#define HSTRIDE   65                  // bf16x8 frag stride in hbuf (1040B)

// Raw workgroup barrier WITHOUT vmcnt drain: waits only this wave's LDS ops,
// then s_barrier. sched_barrier blocks hoisting past the wait (rule #18).
#define WG_BARRIER_NODRAIN()                                   \
    do {                                                       \
        asm volatile("s_waitcnt lgkmcnt(0)" ::: "memory");     \
        __builtin_amdgcn_s_barrier();                          \
        __builtin_amdgcn_sched_barrier(0);                     \
    } while (0)

// ---------------------------------------------------------------------------
// prep: one thread per output ELEMENT (max TLP; W1 reads coalesced over n).
// ---------------------------------------------------------------------------
__global__ void prep_weights(const float* __restrict__ conv_w,
                             const float* __restrict__ W1,
                             const float* __restrict__ W2,
                             const float* __restrict__ W3,
                             bf16_t* __restrict__ W1f,
                             bf16_t* __restrict__ W2f,
                             bf16_t* __restrict__ W3f) {
    int idx = blockIdx.x * 256 + threadIdx.x;
    if (idx < 800 * 320) {
        int k = idx / 320;
        int n = idx - k * 320;
        float v = 0.0f;
        if (k < 784 && n < 300) {
            int py = k / 28;
            int px = k - py * 28;
#pragma unroll
            for (int ky = 0; ky < 3; ++ky) {
                int oy = py - ky;
                if (oy < 0 || oy > 25) continue;
#pragma unroll
                for (int kx = 0; kx < 3; ++kx) {
                    int ox = px - kx;
                    if (ox < 0 || ox > 25) continue;
                    v += conv_w[ky * 3 + kx] * W1[(oy * 26 + ox) * 300 + n];
                }
            }
        }
        int kc = k >> 5, quad = (k >> 3) & 3, j = k & 7;
        int nt = n >> 4, nin = n & 15;
        W1f[(((kc * 20 + nt) * 64 + quad * 16 + nin) << 3) + j] = (bf16_t)v;
    } else if (idx < 800 * 320 + 320 * 320) {
        int i2 = idx - 800 * 320;
        int k = i2 / 320;
        int n = i2 - k * 320;
        float v = (k < 300 && n < 300) ? W2[k * 300 + n] : 0.0f;
        int kc = k >> 5, quad = (k >> 3) & 3, j = k & 7;
        int nt = n >> 4, nin = n & 15;
        W2f[(((kc * 20 + nt) * 64 + quad * 16 + nin) << 3) + j] = (bf16_t)v;
    } else if (idx < 800 * 320 + 320 * 320 + 320 * 16) {
        int i3 = idx - (800 * 320 + 320 * 320);
        int k = i3 / 16;
        int n = i3 - k * 16;
        float v = (k < 300 && n < 10) ? W3[k * 10 + n] : 0.0f;
        int kc = k >> 5, quad = (k >> 3) & 3, j = k & 7;
        W3f[(((kc * 64) + quad * 16 + n) << 3) + j] = (bf16_t)v;
    }
}

// ---------------------------------------------------------------------------
// Fused: out = relu(relu(x@W1eff+b1)@W2+b2)@W3+b3.
// Block = 32 rows, 256 thr (4 waves). Wave w: m-tiles {0,1} x n-tiles
// [w*5, w*5+5). B-frags straight from global (L2-hot).
// ---------------------------------------------------------------------------
__global__ __launch_bounds__(256, 5) void fused_mlp(
    const float* __restrict__ x, const float* __restrict__ b1,
    const float* __restrict__ b2, const float* __restrict__ b3,
    const bf16x8* __restrict__ W1f, const bf16x8* __restrict__ W2f,
    const bf16x8* __restrict__ W3f, float* __restrict__ out) {
    // union: Abuf (2 x 32 x ASTRIDE bf16 = 17408B) overlays hbuf
    // ([20][HSTRIDE] bf16x8 = 20784B). hbuf written only after GEMM1.
    __shared__ __align__(16) unsigned char smem[20800];
    bf16_t* AbufBase = (bf16_t*)smem;           // [2][32*ASTRIDE]
    bf16x8* hbuf     = (bf16x8*)smem;           // [frag][HSTRIDE]
    bf16_t* hb       = (bf16_t*)smem;

    const int tid = threadIdx.x;
    const int w   = tid >> 6;
    const int l   = tid & 63;
    const int q   = l >> 4;
    const int l15 = l & 15;
    const int r0  = blockIdx.x * 32;

    const int nt0 = w * 5;  // n-tiles [nt0, nt0+5)

    // stage maps (bands 0-5, 128 cols): row = i*8 + (tid>>5), col4 = tid&31
    const int srow = tid >> 5;
    const int sc4  = tid & 31;
    // band-6 map (32 cols): 32 rows x 8 float4 (first 4 valid)
    const int trow = tid >> 3;
    const int tc4  = tid & 7;

    float4 pf[4];
#pragma unroll
    for (int i = 0; i < 4; ++i)
        pf[i] = *(const float4*)(x + (size_t)(r0 + i * 8 + srow) * 784 + sc4 * 4);

    f32x4 acc[2][5];
#pragma unroll
    for (int m = 0; m < 2; ++m)
#pragma unroll
        for (int j = 0; j < 5; ++j) acc[m][j] = (f32x4){0.f, 0.f, 0.f, 0.f};

    const bf16x8* bB1 = W1f + nt0 * 64 + l;

    // ---------------- GEMM1: 1 raw barrier per band, pf stays in flight ----
    int kc = 0;
    for (int band = 0; band < 7; ++band) {
        bf16_t* ab = AbufBase + (band & 1) * (32 * ASTRIDE);

        if (band < 6) {
#pragma unroll
            for (int i = 0; i < 4; ++i) {
                bf16x4 v;
                v[0] = (bf16_t)pf[i].x; v[1] = (bf16_t)pf[i].y;
                v[2] = (bf16_t)pf[i].z; v[3] = (bf16_t)pf[i].w;
                *(bf16x4*)&ab[(i * 8 + srow) * ASTRIDE + sc4 * 4] = v;
            }
        } else {
            bf16x4 v;
            v[0] = (bf16_t)pf[0].x; v[1] = (bf16_t)pf[0].y;
            v[2] = (bf16_t)pf[0].z; v[3] = (bf16_t)pf[0].w;
            *(bf16x4*)&ab[trow * ASTRIDE + tc4 * 4] = v;
        }

        // next band's pf: crosses only raw barriers -> stays in flight
        if (band + 1 < 6) {
#pragma unroll
            for (int i = 0; i < 4; ++i)
                pf[i] = *(const float4*)(x + (size_t)(r0 + i * 8 + srow) * 784 +
                                         (band + 1) * 128 + sc4 * 4);
        } else if (band + 1 == 6) {
            pf[0] = (tc4 < 4)
                ? *(const float4*)(x + (size_t)(r0 + trow) * 784 + 768 + tc4 * 4)
                : make_float4(0.f, 0.f, 0.f, 0.f);
        }

        WG_BARRIER_NODRAIN();

#define G1CHUNK(KCL)                                                            \
        {                                                                       \
            bf16x8 a0 = *(const bf16x8*)&ab[( 0 + l15) * ASTRIDE + (KCL) * 32 + q * 8]; \
            bf16x8 a1 = *(const bf16x8*)&ab[(16 + l15) * ASTRIDE + (KCL) * 32 + q * 8]; \
            const bf16x8* bp = bB1 + kc * 1280;                                 \
            bf16x8 b0 = bp[0], b1v = bp[64], b2v = bp[128];                     \
            bf16x8 b3v = bp[192], b4v = bp[256];                                \
            acc[0][0] = MFMA16(a0, b0, acc[0][0]);                              \
            acc[1][0] = MFMA16(a1, b0, acc[1][0]);                              \
            acc[0][1] = MFMA16(a0, b1v, acc[0][1]);                             \
            acc[1][1] = MFMA16(a1, b1v, acc[1][1]);                             \
            acc[0][2] = MFMA16(a0, b2v, acc[0][2]);                             \
            acc[1][2] = MFMA16(a1, b2v, acc[1][2]);                             \
            acc[0][3] = MFMA16(a0, b3v, acc[0][3]);                             \
            acc[1][3] = MFMA16(a1, b3v, acc[1][3]);                             \
            acc[0][4] = MFMA16(a0, b4v, acc[0][4]);                             \
            acc[1][4] = MFMA16(a1, b4v, acc[1][4]);                             \
            ++kc;                                                               \
        }

        if (band < 6) {
            G1CHUNK(0) G1CHUNK(1) G1CHUNK(2) G1CHUNK(3)
        } else {
            G1CHUNK(0)
        }
    }

    WG_BARRIER_NODRAIN();  // all waves done reading Abuf before hbuf overlay

    // ---------------- h1 = relu(C1+b1) -> hbuf (A-frag order, padded) ------
#define HSTORE(J, BIAS)                                                         \
    {                                                                           \
        int n = (nt0 + (J)) * 16 + l15;                                         \
        float bias = (n < 300) ? (BIAS)[n] : 0.0f;                              \
        int kh = n >> 5, quad = (n >> 3) & 3, jj = n & 7;                       \
        _Pragma("unroll")                                                       \
        for (int mt = 0; mt < 2; ++mt)                                          \
            _Pragma("unroll")                                                   \
            for (int r = 0; r < 4; ++r) {                                       \
                float v = acc[mt][(J)][r] + bias;                               \
                v = v > 0.f ? v : 0.f;                                          \
                hb[(((kh * 2 + mt) * HSTRIDE + quad * 16 + q * 4 + r) << 3) +   \
                   jj] = (bf16_t)v;                                             \
            }                                                                   \
    }

    HSTORE(0, b1) HSTORE(1, b1) HSTORE(2, b1) HSTORE(3, b1) HSTORE(4, b1)
    WG_BARRIER_NODRAIN();  // h1 visible

    // ---------------- GEMM2: barrier-free; W2f frags from global (L2) ------
#pragma unroll
    for (int m = 0; m < 2; ++m)
#pragma unroll
        for (int j = 0; j < 5; ++j) acc[m][j] = (f32x4){0.f, 0.f, 0.f, 0.f};

    const bf16x8* bB2 = W2f + nt0 * 64 + l;

#define G2CHUNK(KC2)                                                            \
    {                                                                           \
        bf16x8 a0 = hbuf[((KC2) * 2 + 0) * HSTRIDE + l];                        \
        bf16x8 a1 = hbuf[((KC2) * 2 + 1) * HSTRIDE + l];                        \
        const bf16x8* bp = bB2 + (KC2) * 1280;                                  \
        bf16x8 b0 = bp[0], b1v = bp[64], b2v = bp[128];                         \
        bf16x8 b3v = bp[192], b4v = bp[256];                                    \
        acc[0][0] = MFMA16(a0, b0, acc[0][0]);                                  \
        acc[1][0] = MFMA16(a1, b0, acc[1][0]);                                  \
        acc[0][1] = MFMA16(a0, b1v, acc[0][1]);                                 \
        acc[1][1] = MFMA16(a1, b1v, acc[1][1]);                                 \
        acc[0][2] = MFMA16(a0, b2v, acc[0][2]);                                 \
        acc[1][2] = MFMA16(a1, b2v, acc[1][2]);                                 \
        acc[0][3] = MFMA16(a0, b3v, acc[0][3]);                                 \
        acc[1][3] = MFMA16(a1, b3v, acc[1][3]);                                 \
        acc[0][4] = MFMA16(a0, b4v, acc[0][4]);                                 \
        acc[1][4] = MFMA16(a1, b4v, acc[1][4]);                                 \
    }

    G2CHUNK(0) G2CHUNK(1) G2CHUNK(2) G2CHUNK(3) G2CHUNK(4)
    G2CHUNK(5) G2CHUNK(6) G2CHUNK(7) G2CHUNK(8) G2CHUNK(9)

    WG_BARRIER_NODRAIN();  // all hbuf(h1) reads done before h2 overwrite

    // ---------------- h2 = relu(C2+b2) -> hbuf -----------------------------
    HSTORE(0, b2) HSTORE(1, b2) HSTORE(2, b2) HSTORE(3, b2) HSTORE(4, b2)
    WG_BARRIER_NODRAIN();  // h2 visible

    // ---------------- GEMM3: waves 0-1 (mt=w); W3f frags from global -------
    if (w < 2) {
        f32x4 acc3 = (f32x4){0.f, 0.f, 0.f, 0.f};
#pragma unroll
        for (int kc3 = 0; kc3 < 10; ++kc3)
            acc3 = MFMA16(hbuf[(kc3 * 2 + w) * HSTRIDE + l],
                          W3f[kc3 * 64 + l], acc3);
        if (l15 < 10) {
            float bias = b3[l15];
#pragma unroll
            for (int r = 0; r < 4; ++r)
                out[(size_t)(r0 + w * 16 + q * 4 + r) * 10 + l15] = acc3[r] + bias;
        }
    }
}

// ---------------------------------------------------------------------------
extern "C" void kernel_launch(void* const* d_in, const int* in_sizes, int n_in,
                              void* d_out, int out_size, void* d_ws, size_t ws_size,
                              hipStream_t stream) {
    const float* x      = (const float*)d_in[0];
    const float* conv_w = (const float*)d_in[1];
    const float* W1     = (const float*)d_in[2];
    const float* b1     = (const float*)d_in[3];
    const float* W2     = (const float*)d_in[4];
    const float* b2     = (const float*)d_in[5];
    const float* W3     = (const float*)d_in[6];
    const float* b3     = (const float*)d_in[7];
    float* out = (float*)d_out;

    char* ws = (char*)d_ws;
    bf16_t* W1f = (bf16_t*)(ws);
    bf16_t* W2f = (bf16_t*)(ws + (size_t)W1F_ELEMS * 2);
    bf16_t* W3f = (bf16_t*)(ws + (size_t)(W1F_ELEMS + W2F_ELEMS) * 2);
    if (ws_size < (size_t)(W1F_ELEMS + W2F_ELEMS + W3F_ELEMS) * 2) return;

    int prep_total = 800 * 320 + 320 * 320 + 320 * 16;  // 363520
    prep_weights<<<(prep_total + 255) / 256, 256, 0, stream>>>(
        conv_w, W1, W2, W3, W1f, W2f, W3f);

    fused_mlp<<<32768 / 32, 256, 0, stream>>>(
        x, b1, b2, b3, (const bf16x8*)W1f, (const bf16x8*)W2f,
        (const bf16x8*)W3f, out);
}

// Round 5
// 191.869 us; speedup vs baseline: 1.0254x; 1.0254x over previous
//
#include <hip/hip_runtime.h>

// ---------------------------------------------------------------------------
// DigitConvolutionalModel: x(32768,784) -> conv3x3(valid) -> 676
//   -> relu(@W1(676,300)+b1) -> relu(@W2(300,300)+b2) -> @W3(300,10)+b3
//
// R11 = R10 with the OOB fix (R10 crashed the container: band-12 staged x
// cols 784..799, which for row 32767 reads 60B past the page-aligned end of
// x -> GPU fault). Pad lanes now clamp to an in-bounds address; their values
// are finite garbage multiplied by W1f's zeroed k>=784 rows -> 0.
//
// R10 design (unchanged):
//  - x staged f32 via global_load_lds (16B/lane, no VGPR, no cvt on store
//    path) into a 3-slot ring of 64-col bands (13 bands over K=800),
//    issued TWO bands ahead; counted s_waitcnt vmcnt(N) (never drain) + raw
//    s_barrier per band. N derived from issue order (over-wait-safe).
//  - Source-side XOR swizzle (unit ^= row&7), linear LDS dest (m104/m173),
//    same XOR on ds_read -> ~2-way conflicts.
//  - f32->bf16 cvt at A-frag read (VALU was 10% busy).
//  - 8 waves, 4m x (3|2)n per wave, B frags global (L2-hot), hbuf tail.
//    LDS 48KB (hbuf overlays ring after G1) -> 2 blocks/CU.
//  - prep: per-element (R6/R9 version).
//  - Spill tripwire: WRITE_SIZE must stay ~1.3MB (R9 spilled 11MB).
// ---------------------------------------------------------------------------

typedef __bf16 bf16_t;
typedef __bf16 bf16x8 __attribute__((ext_vector_type(8)));
typedef float  f32x4  __attribute__((ext_vector_type(4)));

#define MFMA16(a, b, c) __builtin_amdgcn_mfma_f32_16x16x32_bf16((a), (b), (c), 0, 0, 0)

#define W1F_ELEMS (25 * 20 * 64 * 8)  // 256000  (K=800, N=320)
#define W2F_ELEMS (10 * 20 * 64 * 8)  // 102400  (K=320, N=320)
#define W3F_ELEMS (10 * 1 * 64 * 8)   // 5120    (K=320, N=16)

#define SLOT_BYTES 16384  // 64 rows x 256B (64 f32 cols)

// ---------------------------------------------------------------------------
__global__ void prep_weights(const float* __restrict__ conv_w,
                             const float* __restrict__ W1,
                             const float* __restrict__ W2,
                             const float* __restrict__ W3,
                             bf16_t* __restrict__ W1f,
                             bf16_t* __restrict__ W2f,
                             bf16_t* __restrict__ W3f) {
    int idx = blockIdx.x * 256 + threadIdx.x;
    if (idx < 800 * 320) {
        int k = idx / 320;
        int n = idx - k * 320;
        float v = 0.0f;
        if (k < 784 && n < 300) {
            int py = k / 28;
            int px = k - py * 28;
#pragma unroll
            for (int ky = 0; ky < 3; ++ky) {
                int oy = py - ky;
                if (oy < 0 || oy > 25) continue;
#pragma unroll
                for (int kx = 0; kx < 3; ++kx) {
                    int ox = px - kx;
                    if (ox < 0 || ox > 25) continue;
                    v += conv_w[ky * 3 + kx] * W1[(oy * 26 + ox) * 300 + n];
                }
            }
        }
        int kc = k >> 5, quad = (k >> 3) & 3, j = k & 7;
        int nt = n >> 4, nin = n & 15;
        W1f[(((kc * 20 + nt) * 64 + quad * 16 + nin) << 3) + j] = (bf16_t)v;
    } else if (idx < 800 * 320 + 320 * 320) {
        int i2 = idx - 800 * 320;
        int k = i2 / 320;
        int n = i2 - k * 320;
        float v = (k < 300 && n < 300) ? W2[k * 300 + n] : 0.0f;
        int kc = k >> 5, quad = (k >> 3) & 3, j = k & 7;
        int nt = n >> 4, nin = n & 15;
        W2f[(((kc * 20 + nt) * 64 + quad * 16 + nin) << 3) + j] = (bf16_t)v;
    } else if (idx < 800 * 320 + 320 * 320 + 320 * 16) {
        int i3 = idx - (800 * 320 + 320 * 320);
        int k = i3 / 16;
        int n = i3 - k * 16;
        float v = (k < 300 && n < 10) ? W3[k * 10 + n] : 0.0f;
        int kc = k >> 5, quad = (k >> 3) & 3, j = k & 7;
        W3f[(((kc * 64) + quad * 16 + n) << 3) + j] = (bf16_t)v;
    }
}

// async global -> LDS, 16B/lane; lds base wave-uniform, global addr per-lane.
__device__ __forceinline__ void stage16(const void* g, void* l) {
    __builtin_amdgcn_global_load_lds(
        (const __attribute__((address_space(1))) void*)g,
        (__attribute__((address_space(3))) void*)l, 16, 0, 0);
}

// ---------------------------------------------------------------------------
// Fused kernel. Block = 64 rows, 512 thr (8 waves). Wave w: 4 m-tiles x
// (3|2) n-tiles. x staged f32 in a 3-slot band ring (64 cols/band).
// ---------------------------------------------------------------------------
__global__ __launch_bounds__(512, 4) void fused_mlp(
    const float* __restrict__ x, const float* __restrict__ b1,
    const float* __restrict__ b2, const float* __restrict__ b3,
    const bf16x8* __restrict__ W1f, const bf16x8* __restrict__ W2f,
    const bf16x8* __restrict__ W3f, float* __restrict__ out) {
    __shared__ __align__(16) unsigned char smem[3 * SLOT_BYTES];  // 48 KB
    bf16x8* hbuf = (bf16x8*)smem;  // 40 KB overlay after G1
    bf16_t* hb   = (bf16_t*)smem;

    const int tid = threadIdx.x;
    const int w   = tid >> 6;
    const int l   = tid & 63;
    const int q   = l >> 4;
    const int l15 = l & 15;
    const int r0  = blockIdx.x * 64;

    const bool t3    = (w < 4);
    const int  nt0   = t3 ? (w * 3) : (12 + (w - 4) * 2);
    const int  boff2 = t3 ? 128 : 64;  // 3rd-tile offset (dup of 2nd if 2-tile)

    f32x4 acc[4][3];
#pragma unroll
    for (int m = 0; m < 4; ++m)
#pragma unroll
        for (int j = 0; j < 3; ++j) acc[m][j] = (f32x4){0.f, 0.f, 0.f, 0.f};

    const bf16x8* bB1 = W1f + nt0 * 64 + l;

    // ---- staging: wave w owns rows [w*8, w*8+8) of each band -------------
    // bands 0..11: 64 f32 cols, 2 instr/wave; band 12: 32 cols, 1 instr.
    // Band-12 pad lanes (u_>=4 would be cols>=784) clamp to col 0 of the
    // same row: in-bounds finite garbage x zeroed W1f rows = 0. (OOB fix.)
#define STAGE_BAND(BAND)                                                       \
    {                                                                          \
        unsigned char* slot_ = smem + ((BAND) % 3) * SLOT_BYTES;               \
        if ((BAND) < 12) {                                                     \
            _Pragma("unroll")                                                  \
            for (int i_ = 0; i_ < 2; ++i_) {                                   \
                int row_ = w * 8 + i_ * 4 + (l >> 4);                          \
                int u_   = (l & 15) ^ (row_ & 7);                              \
                stage16(x + (size_t)(r0 + row_) * 784 + (BAND) * 64 + u_ * 4,  \
                        slot_ + w * 2048 + i_ * 1024);                         \
            }                                                                  \
        } else {                                                               \
            int row_ = w * 8 + (l >> 3);                                       \
            int u_   = (l & 7) ^ (row_ & 7);                                   \
            const float* src_ = x + (size_t)(r0 + row_) * 784 +                \
                                ((u_ < 4) ? (768 + u_ * 4) : 0);               \
            stage16(src_, slot_ + w * 1024);                                   \
        }                                                                      \
    }

    // ---- A fragment: 2x ds_read_b128 f32 (swizzled) + cvt to bf16x8 ------
#define AFRAG(DST, SLOT, RS, KCL, MT)                                          \
    {                                                                          \
        int row_ = (MT) * 16 + l15;                                            \
        int r7_  = row_ & 7;                                                   \
        float4 fa_ = *(const float4*)((SLOT) + row_ * (RS) +                   \
                     ((((KCL) * 8 + q * 2 + 0) ^ r7_) << 4));                  \
        float4 fb_ = *(const float4*)((SLOT) + row_ * (RS) +                   \
                     ((((KCL) * 8 + q * 2 + 1) ^ r7_) << 4));                  \
        bf16x8 t_;                                                             \
        t_[0] = (bf16_t)fa_.x; t_[1] = (bf16_t)fa_.y;                          \
        t_[2] = (bf16_t)fa_.z; t_[3] = (bf16_t)fa_.w;                          \
        t_[4] = (bf16_t)fb_.x; t_[5] = (bf16_t)fb_.y;                          \
        t_[6] = (bf16_t)fb_.z; t_[7] = (bf16_t)fb_.w;                          \
        DST = t_;                                                              \
    }

#define G1CHUNK(SLOT, RS, KCL, KC)                                             \
    {                                                                          \
        bf16x8 a0, a1, a2, a3;                                                 \
        AFRAG(a0, SLOT, RS, KCL, 0) AFRAG(a1, SLOT, RS, KCL, 1)                \
        AFRAG(a2, SLOT, RS, KCL, 2) AFRAG(a3, SLOT, RS, KCL, 3)                \
        const bf16x8* bp = bB1 + (KC) * 1280;                                  \
        bf16x8 b0 = bp[0], b1v = bp[64], b2v = bp[boff2];                      \
        acc[0][0] = MFMA16(a0, b0, acc[0][0]);                                 \
        acc[1][0] = MFMA16(a1, b0, acc[1][0]);                                 \
        acc[2][0] = MFMA16(a2, b0, acc[2][0]);                                 \
        acc[3][0] = MFMA16(a3, b0, acc[3][0]);                                 \
        acc[0][1] = MFMA16(a0, b1v, acc[0][1]);                                \
        acc[1][1] = MFMA16(a1, b1v, acc[1][1]);                                \
        acc[2][1] = MFMA16(a2, b1v, acc[2][1]);                                \
        acc[3][1] = MFMA16(a3, b1v, acc[3][1]);                                \
        if (t3) {                                                              \
            acc[0][2] = MFMA16(a0, b2v, acc[0][2]);                            \
            acc[1][2] = MFMA16(a1, b2v, acc[1][2]);                            \
            acc[2][2] = MFMA16(a2, b2v, acc[2][2]);                            \
            acc[3][2] = MFMA16(a3, b2v, acc[3][2]);                            \
        }                                                                      \
    }

#define VMW(N) asm volatile("s_waitcnt vmcnt(" #N ") lgkmcnt(0)" ::: "memory")
#define BARRIER()                         \
    __builtin_amdgcn_s_barrier();         \
    __builtin_amdgcn_sched_barrier(0)

    // ---------------- GEMM1: 13 bands, ring-3, staged 2 ahead --------------
    STAGE_BAND(0)
    STAGE_BAND(1)

    // band 0: newer-than-S(0) = S(1)=2
    VMW(2);
    BARRIER();
    STAGE_BAND(2)
    __builtin_amdgcn_sched_barrier(0);
    {
        unsigned char* s0 = smem;
        G1CHUNK(s0, 256, 0, 0)
        G1CHUNK(s0, 256, 1, 1)
    }

    // bands 1..10: newer-than-S(b) = S(b+1):2 + B(b-1):6|4
    for (int band = 1; band <= 10; ++band) {
        if (t3) { VMW(8); } else { VMW(6); }
        BARRIER();
        STAGE_BAND(band + 2)
        __builtin_amdgcn_sched_barrier(0);
        unsigned char* sb = smem + (band % 3) * SLOT_BYTES;
        int kc = band * 2;
        G1CHUNK(sb, 256, 0, kc)
        G1CHUNK(sb, 256, 1, kc + 1)
    }

    // band 11: newer-than-S(11) = S(12):1 + B(10):6|4
    if (t3) { VMW(7); } else { VMW(5); }
    BARRIER();
    {
        unsigned char* sb = smem + (11 % 3) * SLOT_BYTES;
        G1CHUNK(sb, 256, 0, 22)
        G1CHUNK(sb, 256, 1, 23)
    }

    // band 12: newer-than-S(12) = B(11):6|4  (32 cols, row stride 128)
    if (t3) { VMW(6); } else { VMW(4); }
    BARRIER();
    {
        unsigned char* sb = smem + (12 % 3) * SLOT_BYTES;
        G1CHUNK(sb, 128, 0, 24)
    }

    // all ring reads done before hbuf overlay
    asm volatile("s_waitcnt lgkmcnt(0)" ::: "memory");
    BARRIER();

    // ---------------- h1 = relu(C1+b1) -> hbuf (A-frag order) --------------
#define HSTORE(J, BIAS)                                                        \
    {                                                                          \
        int n = (nt0 + (J)) * 16 + l15;                                        \
        float bias = (n < 300) ? (BIAS)[n] : 0.0f;                             \
        int kh = n >> 5, quad = (n >> 3) & 3, jj = n & 7;                      \
        _Pragma("unroll")                                                      \
        for (int mt = 0; mt < 4; ++mt)                                         \
            _Pragma("unroll")                                                  \
            for (int r = 0; r < 4; ++r) {                                      \
                float v = acc[mt][(J)][r] + bias;                              \
                v = v > 0.f ? v : 0.f;                                         \
                hb[(((kh * 4 + mt) * 64 + quad * 16 + q * 4 + r) << 3) + jj] = \
                    (bf16_t)v;                                                 \
            }                                                                  \
    }

    HSTORE(0, b1)
    HSTORE(1, b1)
    if (t3) HSTORE(2, b1)
    asm volatile("s_waitcnt lgkmcnt(0)" ::: "memory");
    BARRIER();  // h1 visible

    // ---------------- GEMM2: barrier-free; W2f frags from global (L2) ------
#pragma unroll
    for (int m = 0; m < 4; ++m)
#pragma unroll
        for (int j = 0; j < 3; ++j) acc[m][j] = (f32x4){0.f, 0.f, 0.f, 0.f};

    const bf16x8* bB2 = W2f + nt0 * 64 + l;

#define G2CHUNK(KC2)                                                           \
    {                                                                          \
        bf16x8 a0 = hbuf[((KC2) * 4 + 0) * 64 + l];                            \
        bf16x8 a1 = hbuf[((KC2) * 4 + 1) * 64 + l];                            \
        bf16x8 a2 = hbuf[((KC2) * 4 + 2) * 64 + l];                            \
        bf16x8 a3 = hbuf[((KC2) * 4 + 3) * 64 + l];                            \
        const bf16x8* bp = bB2 + (KC2) * 1280;                                 \
        bf16x8 b0 = bp[0], b1v = bp[64], b2v = bp[boff2];                      \
        acc[0][0] = MFMA16(a0, b0, acc[0][0]);                                 \
        acc[1][0] = MFMA16(a1, b0, acc[1][0]);                                 \
        acc[2][0] = MFMA16(a2, b0, acc[2][0]);                                 \
        acc[3][0] = MFMA16(a3, b0, acc[3][0]);                                 \
        acc[0][1] = MFMA16(a0, b1v, acc[0][1]);                                \
        acc[1][1] = MFMA16(a1, b1v, acc[1][1]);                                \
        acc[2][1] = MFMA16(a2, b1v, acc[2][1]);                                \
        acc[3][1] = MFMA16(a3, b1v, acc[3][1]);                                \
        if (t3) {                                                              \
            acc[0][2] = MFMA16(a0, b2v, acc[0][2]);                            \
            acc[1][2] = MFMA16(a1, b2v, acc[1][2]);                            \
            acc[2][2] = MFMA16(a2, b2v, acc[2][2]);                            \
            acc[3][2] = MFMA16(a3, b2v, acc[3][2]);                            \
        }                                                                      \
    }

    G2CHUNK(0) G2CHUNK(1) G2CHUNK(2) G2CHUNK(3) G2CHUNK(4)
    G2CHUNK(5) G2CHUNK(6) G2CHUNK(7) G2CHUNK(8) G2CHUNK(9)

    asm volatile("s_waitcnt lgkmcnt(0)" ::: "memory");
    BARRIER();  // h1 reads done before h2 overwrite

    // ---------------- h2 = relu(C2+b2) -> hbuf -----------------------------
    HSTORE(0, b2)
    HSTORE(1, b2)
    if (t3) HSTORE(2, b2)
    asm volatile("s_waitcnt lgkmcnt(0)" ::: "memory");
    BARRIER();  // h2 visible

    // ---------------- GEMM3: waves 0-3 (mt=w); W3f frags from global -------
    if (w < 4) {
        f32x4 acc3 = (f32x4){0.f, 0.f, 0.f, 0.f};
#pragma unroll
        for (int kc3 = 0; kc3 < 10; ++kc3)
            acc3 = MFMA16(hbuf[(kc3 * 4 + w) * 64 + l], W3f[kc3 * 64 + l], acc3);
        if (l15 < 10) {
            float bias = b3[l15];
#pragma unroll
            for (int r = 0; r < 4; ++r)
                out[(size_t)(r0 + w * 16 + q * 4 + r) * 10 + l15] = acc3[r] + bias;
        }
    }
}

// ---------------------------------------------------------------------------
extern "C" void kernel_launch(void* const* d_in, const int* in_sizes, int n_in,
                              void* d_out, int out_size, void* d_ws, size_t ws_size,
                              hipStream_t stream) {
    const float* x      = (const float*)d_in[0];
    const float* conv_w = (const float*)d_in[1];
    const float* W1     = (const float*)d_in[2];
    const float* b1     = (const float*)d_in[3];
    const float* W2     = (const float*)d_in[4];
    const float* b2     = (const float*)d_in[5];
    const float* W3     = (const float*)d_in[6];
    const float* b3     = (const float*)d_in[7];
    float* out = (float*)d_out;

    char* ws = (char*)d_ws;
    bf16_t* W1f = (bf16_t*)(ws);
    bf16_t* W2f = (bf16_t*)(ws + (size_t)W1F_ELEMS * 2);
    bf16_t* W3f = (bf16_t*)(ws + (size_t)(W1F_ELEMS + W2F_ELEMS) * 2);
    if (ws_size < (size_t)(W1F_ELEMS + W2F_ELEMS + W3F_ELEMS) * 2) return;

    int prep_total = 800 * 320 + 320 * 320 + 320 * 16;  // 363520
    prep_weights<<<(prep_total + 255) / 256, 256, 0, stream>>>(
        conv_w, W1, W2, W3, W1f, W2f, W3f);

    fused_mlp<<<32768 / 64, 512, 0, stream>>>(
        x, b1, b2, b3, (const bf16x8*)W1f, (const bf16x8*)W2f,
        (const bf16x8*)W3f, out);
}

// Round 6
// 181.210 us; speedup vs baseline: 1.0857x; 1.0588x over previous
//
#include <hip/hip_runtime.h>

// ---------------------------------------------------------------------------
// DigitConvolutionalModel: x(32768,784) -> conv3x3(valid) -> 676
//   -> relu(@W1(676,300)+b1) -> relu(@W2(300,300)+b2) -> @W3(300,10)+b3
//
// R12: kill the compiler's per-chunk vmcnt(0) drains.
//  ROOT CAUSE (R7-R11): B-frags were VGPR global loads issued AFTER the
//  staging global_load_lds ops; consuming the youngest B forces the
//  compiler to emit s_waitcnt vmcnt(0) -> drains the ENTIRE staging queue
//  every chunk (25x). Evidence: R11 replays with x L3-resident (2.4MB HBM)
//  still took 65us -> pure in-kernel serialization, all pipes <15%.
//  FIX: B1 chunks also staged via global_load_lds (dbuf, 1 chunk ahead);
//  ALL GEMM1 global traffic is async-to-LDS, ALL consumption is ds_read
//  (lgkmcnt). Only vmcnt waits in GEMM1 are explicit counted literals:
//  VMW(2) after even chunks (x-band stage stays in flight), VMW(0) after
//  odd chunks, VMW(1) at the band-12 edge. Raw s_barrier (no drain).
//  - LDS 72KB: Bbuf dbuf 40KB + x ring-2 32KB; hbuf overlays Bbuf in tail.
//    2 blocks/CU.
//  - B-stage split: waves 0-3 (3 n-tiles of MFMA) stage 2 groups, waves
//    4-7 stage 3 -> per-SIMD balanced.
//  - x staging/swizzle/AFRAG = R11 (verified). Tail = R11 (global W2f/W3f).
//  - Spill tripwire: WRITE_SIZE must stay ~1.3-2.3MB.
// ---------------------------------------------------------------------------

typedef __bf16 bf16_t;
typedef __bf16 bf16x8 __attribute__((ext_vector_type(8)));
typedef float  f32x4  __attribute__((ext_vector_type(4)));

#define MFMA16(a, b, c) __builtin_amdgcn_mfma_f32_16x16x32_bf16((a), (b), (c), 0, 0, 0)

#define W1F_ELEMS (25 * 20 * 64 * 8)  // 256000  (K=800, N=320)
#define W2F_ELEMS (10 * 20 * 64 * 8)  // 102400  (K=320, N=320)
#define W3F_ELEMS (10 * 1 * 64 * 8)   // 5120    (K=320, N=16)

#define XSLOT 16384   // one x band: 64 rows x 256B (64 f32 cols)
#define XBASE 40960   // Bbuf = 2 * 1280 frags * 16B = 40960B

// ---------------------------------------------------------------------------
__global__ void prep_weights(const float* __restrict__ conv_w,
                             const float* __restrict__ W1,
                             const float* __restrict__ W2,
                             const float* __restrict__ W3,
                             bf16_t* __restrict__ W1f,
                             bf16_t* __restrict__ W2f,
                             bf16_t* __restrict__ W3f) {
    int idx = blockIdx.x * 256 + threadIdx.x;
    if (idx < 800 * 320) {
        int k = idx / 320;
        int n = idx - k * 320;
        float v = 0.0f;
        if (k < 784 && n < 300) {
            int py = k / 28;
            int px = k - py * 28;
#pragma unroll
            for (int ky = 0; ky < 3; ++ky) {
                int oy = py - ky;
                if (oy < 0 || oy > 25) continue;
#pragma unroll
                for (int kx = 0; kx < 3; ++kx) {
                    int ox = px - kx;
                    if (ox < 0 || ox > 25) continue;
                    v += conv_w[ky * 3 + kx] * W1[(oy * 26 + ox) * 300 + n];
                }
            }
        }
        int kc = k >> 5, quad = (k >> 3) & 3, j = k & 7;
        int nt = n >> 4, nin = n & 15;
        W1f[(((kc * 20 + nt) * 64 + quad * 16 + nin) << 3) + j] = (bf16_t)v;
    } else if (idx < 800 * 320 + 320 * 320) {
        int i2 = idx - 800 * 320;
        int k = i2 / 320;
        int n = i2 - k * 320;
        float v = (k < 300 && n < 300) ? W2[k * 300 + n] : 0.0f;
        int kc = k >> 5, quad = (k >> 3) & 3, j = k & 7;
        int nt = n >> 4, nin = n & 15;
        W2f[(((kc * 20 + nt) * 64 + quad * 16 + nin) << 3) + j] = (bf16_t)v;
    } else if (idx < 800 * 320 + 320 * 320 + 320 * 16) {
        int i3 = idx - (800 * 320 + 320 * 320);
        int k = i3 / 16;
        int n = i3 - k * 16;
        float v = (k < 300 && n < 10) ? W3[k * 10 + n] : 0.0f;
        int kc = k >> 5, quad = (k >> 3) & 3, j = k & 7;
        W3f[(((kc * 64) + quad * 16 + n) << 3) + j] = (bf16_t)v;
    }
}

// async global -> LDS, 16B/lane; LDS base wave-uniform (HW adds lane*16),
// global addr per-lane.
__device__ __forceinline__ void stage16(const void* g, void* l) {
    __builtin_amdgcn_global_load_lds(
        (const __attribute__((address_space(1))) void*)g,
        (__attribute__((address_space(3))) void*)l, 16, 0, 0);
}

// ---------------------------------------------------------------------------
// Fused kernel. Block = 64 rows, 512 thr (8 waves). Wave w: 4 m-tiles x
// (3|2) n-tiles. B1 chunks LDS-dbuf'd; x f32 bands LDS ring-2.
// ---------------------------------------------------------------------------
__global__ __launch_bounds__(512, 4) void fused_mlp(
    const float* __restrict__ x, const float* __restrict__ b1,
    const float* __restrict__ b2, const float* __restrict__ b3,
    const bf16x8* __restrict__ W1f, const bf16x8* __restrict__ W2f,
    const bf16x8* __restrict__ W3f, float* __restrict__ out) {
    __shared__ __align__(16) unsigned char smem[XBASE + 2 * XSLOT];  // 72 KB
    bf16x8* Bb   = (bf16x8*)smem;  // [2][1280] B1 chunk dbuf
    bf16x8* hbuf = (bf16x8*)smem;  // 40 KB overlay after G1
    bf16_t* hb   = (bf16_t*)smem;

    const int tid = threadIdx.x;
    const int w   = tid >> 6;
    const int l   = tid & 63;
    const int q   = l >> 4;
    const int l15 = l & 15;
    const int r0  = blockIdx.x * 64;

    const bool t3    = (w < 4);
    const int  nt0   = t3 ? (w * 3) : (12 + (w - 4) * 2);
    const int  boff2 = t3 ? 128 : 64;  // 3rd-tile offset (dup of 2nd if 2-tile)

    f32x4 acc[4][3];
#pragma unroll
    for (int m = 0; m < 4; ++m)
#pragma unroll
        for (int j = 0; j < 3; ++j) acc[m][j] = (f32x4){0.f, 0.f, 0.f, 0.f};

    // ---- B1 chunk staging: 20 groups of 64 frags; waves 0-3 take 2 groups
    // ({w, w+8}), waves 4-7 take 3 ({w, w+8, w+12}). Always issued FIRST in
    // a chunk so the x-band stage (issued after) stays in flight at VMW(2).
#define STAGE_B(KC, BUF)                                                       \
    {                                                                          \
        const bf16x8* ws_ = W1f + (size_t)(KC)*1280 + l;                       \
        bf16x8* wd_ = Bb + (BUF)*1280;                                         \
        stage16(ws_ + w * 64, wd_ + w * 64);                                   \
        stage16(ws_ + (w + 8) * 64, wd_ + (w + 8) * 64);                       \
        if (w >= 4) stage16(ws_ + (w + 12) * 64, wd_ + (w + 12) * 64);         \
    }

    // ---- x band staging (R11-verified): 64 f32 cols/band, src-side XOR
    // swizzle (unit ^= row&7), linear LDS dest. Band 12: 32 cols, clamped.
#define STAGE_BAND(BAND)                                                       \
    {                                                                          \
        unsigned char* slot_ = smem + XBASE + ((BAND)&1) * XSLOT;              \
        if ((BAND) < 12) {                                                     \
            _Pragma("unroll")                                                  \
            for (int i_ = 0; i_ < 2; ++i_) {                                   \
                int row_ = w * 8 + i_ * 4 + (l >> 4);                          \
                int u_   = (l & 15) ^ (row_ & 7);                              \
                stage16(x + (size_t)(r0 + row_) * 784 + (BAND)*64 + u_ * 4,    \
                        slot_ + w * 2048 + i_ * 1024);                         \
            }                                                                  \
        } else {                                                               \
            int row_ = w * 8 + (l >> 3);                                       \
            int u_   = (l & 7) ^ (row_ & 7);                                   \
            const float* src_ = x + (size_t)(r0 + row_) * 784 +                \
                                ((u_ < 4) ? (768 + u_ * 4) : 0);               \
            stage16(src_, slot_ + w * 1024);                                   \
        }                                                                      \
    }

    // ---- A fragment: 2x ds_read_b128 f32 (swizzled) + cvt to bf16x8 ------
#define AFRAG(DST, SLOT, RS, KCL, MT)                                          \
    {                                                                          \
        int row_ = (MT)*16 + l15;                                              \
        int r7_  = row_ & 7;                                                   \
        float4 fa_ = *(const float4*)((SLOT) + row_ * (RS) +                   \
                     ((((KCL)*8 + q * 2 + 0) ^ r7_) << 4));                    \
        float4 fb_ = *(const float4*)((SLOT) + row_ * (RS) +                   \
                     ((((KCL)*8 + q * 2 + 1) ^ r7_) << 4));                    \
        bf16x8 t_;                                                             \
        t_[0] = (bf16_t)fa_.x; t_[1] = (bf16_t)fa_.y;                          \
        t_[2] = (bf16_t)fa_.z; t_[3] = (bf16_t)fa_.w;                          \
        t_[4] = (bf16_t)fb_.x; t_[5] = (bf16_t)fb_.y;                          \
        t_[6] = (bf16_t)fb_.z; t_[7] = (bf16_t)fb_.w;                          \
        DST = t_;                                                              \
    }

    // ---- one K=32 chunk: A from x-slot, B from LDS dbuf (ds_read, 1KB
    // contiguous per 64-frag group -> conflict-free), 12|8 MFMA.
#define G1CHUNK(SLOT, RS, KCL, BUF)                                            \
    {                                                                          \
        bf16x8 a0, a1, a2, a3;                                                 \
        AFRAG(a0, SLOT, RS, KCL, 0) AFRAG(a1, SLOT, RS, KCL, 1)                \
        AFRAG(a2, SLOT, RS, KCL, 2) AFRAG(a3, SLOT, RS, KCL, 3)                \
        const bf16x8* bb_ = Bb + (BUF)*1280 + nt0 * 64 + l;                    \
        bf16x8 b0 = bb_[0], b1v = bb_[64], b2v = bb_[boff2];                   \
        acc[0][0] = MFMA16(a0, b0, acc[0][0]);                                 \
        acc[1][0] = MFMA16(a1, b0, acc[1][0]);                                 \
        acc[2][0] = MFMA16(a2, b0, acc[2][0]);                                 \
        acc[3][0] = MFMA16(a3, b0, acc[3][0]);                                 \
        acc[0][1] = MFMA16(a0, b1v, acc[0][1]);                                \
        acc[1][1] = MFMA16(a1, b1v, acc[1][1]);                                \
        acc[2][1] = MFMA16(a2, b1v, acc[2][1]);                                \
        acc[3][1] = MFMA16(a3, b1v, acc[3][1]);                                \
        if (t3) {                                                              \
            acc[0][2] = MFMA16(a0, b2v, acc[0][2]);                            \
            acc[1][2] = MFMA16(a1, b2v, acc[1][2]);                            \
            acc[2][2] = MFMA16(a2, b2v, acc[2][2]);                            \
            acc[3][2] = MFMA16(a3, b2v, acc[3][2]);                            \
        }                                                                      \
    }

#define VMW(N) asm volatile("s_waitcnt vmcnt(" #N ") lgkmcnt(0)" ::: "memory")
#define BARRIER()                         \
    __builtin_amdgcn_s_barrier();         \
    __builtin_amdgcn_sched_barrier(0)

    // ---------------- GEMM1: 25 chunks (bands of 2), all-LDS operands ------
    // prologue: B_0 + X_0; cold-start drain.
    STAGE_B(0, 0)
    STAGE_BAND(0)
    VMW(0);
    BARRIER();

    for (int b = 0; b <= 10; ++b) {
        unsigned char* xs = smem + XBASE + (b & 1) * XSLOT;
        const int k0 = 2 * b;
        // even chunk k0: stage B_{k0+1} then X_{b+1}; compute; keep X in flight
        STAGE_B(k0 + 1, (k0 + 1) & 1)
        STAGE_BAND(b + 1)
        G1CHUNK(xs, 256, 0, k0 & 1)
        VMW(2);
        BARRIER();
        // odd chunk k0+1: stage B_{k0+2}; compute; drain (next chunk needs all)
        STAGE_B(k0 + 2, (k0 + 2) & 1)
        G1CHUNK(xs, 256, 1, (k0 + 1) & 1)
        VMW(0);
        BARRIER();
    }
    // band 11 (chunks 22, 23); stages band 12 (1 op -> VMW(1))
    {
        unsigned char* xs = smem + XBASE + XSLOT;  // slot 1
        STAGE_B(23, 1)
        STAGE_BAND(12)
        G1CHUNK(xs, 256, 0, 0)
        VMW(1);
        BARRIER();
        STAGE_B(24, 0)
        G1CHUNK(xs, 256, 1, 1)
        VMW(0);
        BARRIER();
    }
    // band 12 (chunk 24, 32 cols, row stride 128; slot 0)
    {
        unsigned char* xs = smem + XBASE;
        G1CHUNK(xs, 128, 0, 0)
        asm volatile("s_waitcnt lgkmcnt(0)" ::: "memory");
        BARRIER();  // all Bbuf/x reads done before hbuf overlay
    }

    // ---------------- h1 = relu(C1+b1) -> hbuf (A-frag order) --------------
#define HSTORE(J, BIAS)                                                        \
    {                                                                          \
        int n = (nt0 + (J)) * 16 + l15;                                        \
        float bias = (n < 300) ? (BIAS)[n] : 0.0f;                             \
        int kh = n >> 5, quad = (n >> 3) & 3, jj = n & 7;                      \
        _Pragma("unroll")                                                      \
        for (int mt = 0; mt < 4; ++mt)                                         \
            _Pragma("unroll")                                                  \
            for (int r = 0; r < 4; ++r) {                                      \
                float v = acc[mt][(J)][r] + bias;                              \
                v = v > 0.f ? v : 0.f;                                         \
                hb[(((kh * 4 + mt) * 64 + quad * 16 + q * 4 + r) << 3) + jj] = \
                    (bf16_t)v;                                                 \
            }                                                                  \
    }

    HSTORE(0, b1)
    HSTORE(1, b1)
    if (t3) HSTORE(2, b1)
    asm volatile("s_waitcnt lgkmcnt(0)" ::: "memory");
    BARRIER();  // h1 visible

    // ---------------- GEMM2: barrier-free; W2f frags from global (L2) ------
#pragma unroll
    for (int m = 0; m < 4; ++m)
#pragma unroll
        for (int j = 0; j < 3; ++j) acc[m][j] = (f32x4){0.f, 0.f, 0.f, 0.f};

    const bf16x8* bB2 = W2f + nt0 * 64 + l;

#define G2CHUNK(KC2)                                                           \
    {                                                                          \
        bf16x8 a0 = hbuf[((KC2)*4 + 0) * 64 + l];                              \
        bf16x8 a1 = hbuf[((KC2)*4 + 1) * 64 + l];                              \
        bf16x8 a2 = hbuf[((KC2)*4 + 2) * 64 + l];                              \
        bf16x8 a3 = hbuf[((KC2)*4 + 3) * 64 + l];                              \
        const bf16x8* bp = bB2 + (KC2)*1280;                                   \
        bf16x8 b0 = bp[0], b1v = bp[64], b2v = bp[boff2];                      \
        acc[0][0] = MFMA16(a0, b0, acc[0][0]);                                 \
        acc[1][0] = MFMA16(a1, b0, acc[1][0]);                                 \
        acc[2][0] = MFMA16(a2, b0, acc[2][0]);                                 \
        acc[3][0] = MFMA16(a3, b0, acc[3][0]);                                 \
        acc[0][1] = MFMA16(a0, b1v, acc[0][1]);                                \
        acc[1][1] = MFMA16(a1, b1v, acc[1][1]);                                \
        acc[2][1] = MFMA16(a2, b1v, acc[2][1]);                                \
        acc[3][1] = MFMA16(a3, b1v, acc[3][1]);                                \
        if (t3) {                                                              \
            acc[0][2] = MFMA16(a0, b2v, acc[0][2]);                            \
            acc[1][2] = MFMA16(a1, b2v, acc[1][2]);                            \
            acc[2][2] = MFMA16(a2, b2v, acc[2][2]);                            \
            acc[3][2] = MFMA16(a3, b2v, acc[3][2]);                            \
        }                                                                      \
    }

    G2CHUNK(0) G2CHUNK(1) G2CHUNK(2) G2CHUNK(3) G2CHUNK(4)
    G2CHUNK(5) G2CHUNK(6) G2CHUNK(7) G2CHUNK(8) G2CHUNK(9)

    asm volatile("s_waitcnt lgkmcnt(0)" ::: "memory");
    BARRIER();  // h1 reads done before h2 overwrite

    // ---------------- h2 = relu(C2+b2) -> hbuf -----------------------------
    HSTORE(0, b2)
    HSTORE(1, b2)
    if (t3) HSTORE(2, b2)
    asm volatile("s_waitcnt lgkmcnt(0)" ::: "memory");
    BARRIER();  // h2 visible

    // ---------------- GEMM3: waves 0-3 (mt=w); W3f frags from global -------
    if (w < 4) {
        f32x4 acc3 = (f32x4){0.f, 0.f, 0.f, 0.f};
#pragma unroll
        for (int kc3 = 0; kc3 < 10; ++kc3)
            acc3 = MFMA16(hbuf[(kc3 * 4 + w) * 64 + l], W3f[kc3 * 64 + l], acc3);
        if (l15 < 10) {
            float bias = b3[l15];
#pragma unroll
            for (int r = 0; r < 4; ++r)
                out[(size_t)(r0 + w * 16 + q * 4 + r) * 10 + l15] = acc3[r] + bias;
        }
    }
}

// ---------------------------------------------------------------------------
extern "C" void kernel_launch(void* const* d_in, const int* in_sizes, int n_in,
                              void* d_out, int out_size, void* d_ws, size_t ws_size,
                              hipStream_t stream) {
    const float* x      = (const float*)d_in[0];
    const float* conv_w = (const float*)d_in[1];
    const float* W1     = (const float*)d_in[2];
    const float* b1     = (const float*)d_in[3];
    const float* W2     = (const float*)d_in[4];
    const float* b2     = (const float*)d_in[5];
    const float* W3     = (const float*)d_in[6];
    const float* b3     = (const float*)d_in[7];
    float* out = (float*)d_out;

    char* ws = (char*)d_ws;
    bf16_t* W1f = (bf16_t*)(ws);
    bf16_t* W2f = (bf16_t*)(ws + (size_t)W1F_ELEMS * 2);
    bf16_t* W3f = (bf16_t*)(ws + (size_t)(W1F_ELEMS + W2F_ELEMS) * 2);
    if (ws_size < (size_t)(W1F_ELEMS + W2F_ELEMS + W3F_ELEMS) * 2) return;

    int prep_total = 800 * 320 + 320 * 320 + 320 * 16;  // 363520
    prep_weights<<<(prep_total + 255) / 256, 256, 0, stream>>>(
        conv_w, W1, W2, W3, W1f, W2f, W3f);

    fused_mlp<<<32768 / 64, 512, 0, stream>>>(
        x, b1, b2, b3, (const bf16x8*)W1f, (const bf16x8*)W2f,
        (const bf16x8*)W3f, out);
}